// Round 9
// baseline (132.374 us; speedup 1.0000x reference)
//
#include <hip/hip_runtime.h>
#include <hip/hip_fp16.h>
#include <math.h>

constexpr int   NN     = 50000;   // nodes
constexpr int   IN_DIM = 128;
constexpr int   HID    = 64;
constexpr int   NE     = 800000;  // edges
constexpr float ALPHA  = 0.1520f;
constexpr float BETA   = 0.7900f;

constexpr int RSH = 7;                      // rows per bucket = 128
constexpr int RPB = 1 << RSH;
constexpr int NB  = (NN + RPB - 1) / RPB;   // 391 buckets
constexpr int NBP = 512;                    // padded width
constexpr int CH  = 4096;                   // edges per chunk block
constexpr int NCH = (NE + CH - 1) / CH;     // 196
constexpr int CAP = 4096;                   // per-bucket LDS edge capacity

// ---------------- per-chunk bucket histogram -> bpart[b][chunk] ----------------
__global__ __launch_bounds__(256) void k_bhist(const int* __restrict__ row,
                                               int* __restrict__ bpart) {
    __shared__ int h[NBP];
    int t = threadIdx.x;
    for (int i = t; i < NBP; i += 256) h[i] = 0;
    __syncthreads();
    int base = blockIdx.x * CH + t * 16;
    if (base + 15 < NE) {
        const int4* R = (const int4*)(row + base);
#pragma unroll
        for (int i = 0; i < 4; ++i) {
            int4 r = R[i];
            atomicAdd(&h[r.x >> RSH], 1);
            atomicAdd(&h[r.y >> RSH], 1);
            atomicAdd(&h[r.z >> RSH], 1);
            atomicAdd(&h[r.w >> RSH], 1);
        }
    } else {
        for (int i = 0; i < 16; ++i) {
            int e = base + i;
            if (e < NE) atomicAdd(&h[row[e] >> RSH], 1);
        }
    }
    __syncthreads();
    for (int b = t; b < NB; b += 256) bpart[b * NCH + blockIdx.x] = h[b];
}

// ------- merged: column-sum + in-place chunk-prefix of bpart + bucket scan -> boffs -------
__global__ __launch_bounds__(256) void k_bscan(int* __restrict__ bpart,
                                               int* __restrict__ boffs) {
    __shared__ int s[NBP];
    int t = threadIdx.x;  // 256
    int tot0 = 0, tot1 = 0;
    {   // bucket t (always < NB since NB=391)
        int* p = bpart + (size_t)t * NCH;
        for (int c = 0; c < NCH; ++c) { int v = p[c]; p[c] = tot0; tot0 += v; }
    }
    if (t + 256 < NB) {
        int* p = bpart + (size_t)(t + 256) * NCH;
        for (int c = 0; c < NCH; ++c) { int v = p[c]; p[c] = tot1; tot1 += v; }
    }
    s[t]       = tot0;
    s[t + 256] = (t + 256 < NB) ? tot1 : 0;
    __syncthreads();
    for (int d = 1; d < NBP; d <<= 1) {
        int v0 = (t >= d) ? s[t - d] : 0;
        int v1 = (t + 256 >= d) ? s[t + 256 - d] : 0;
        __syncthreads();
        s[t] += v0;
        s[t + 256] += v1;
        __syncthreads();
    }
    if (t < NB)       boffs[t]       = s[t] - tot0;
    if (t + 256 < NB) boffs[t + 256] = s[t + 256] - tot1;
    if (t == 0) boffs[NB] = NE;
}

// ---------------- bucket-sort edges into packed words (no global atomics) ----------------
__global__ __launch_bounds__(256) void k_binfill(const int* __restrict__ row,
                                                 const int* __restrict__ col,
                                                 const int* __restrict__ bpart,
                                                 const int* __restrict__ boffs,
                                                 unsigned int* __restrict__ bedge) {
    __shared__ int hist[NBP];
    __shared__ int scn[NBP];
    __shared__ int ebase[NB];
    __shared__ int gbase[NB];
    __shared__ int lcur[NB];
    __shared__ unsigned int pk[CH];
    __shared__ int gof[CH];

    int t = threadIdx.x;
    int base = blockIdx.x * CH + t * 16;
    int rw[16], cl[16];
    if (base + 15 < NE) {
        const int4* R = (const int4*)(row + base);
        const int4* C = (const int4*)(col + base);
#pragma unroll
        for (int i = 0; i < 4; ++i) {
            int4 r = R[i];
            int4 c = C[i];
            rw[4 * i + 0] = r.x; rw[4 * i + 1] = r.y; rw[4 * i + 2] = r.z; rw[4 * i + 3] = r.w;
            cl[4 * i + 0] = c.x; cl[4 * i + 1] = c.y; cl[4 * i + 2] = c.z; cl[4 * i + 3] = c.w;
        }
    } else {
        for (int i = 0; i < 16; ++i) {
            int e = base + i;
            if (e < NE) { rw[i] = row[e]; cl[i] = col[e]; } else rw[i] = -1;
        }
    }
    for (int i = t; i < NBP; i += 256) hist[i] = 0;
    __syncthreads();
#pragma unroll
    for (int i = 0; i < 16; ++i)
        if (rw[i] >= 0) atomicAdd(&hist[rw[i] >> RSH], 1);
    __syncthreads();
    scn[t] = hist[t];
    scn[t + 256] = hist[t + 256];
    __syncthreads();
    for (int d = 1; d < NBP; d <<= 1) {
        int v0 = (t >= d) ? scn[t - d] : 0;
        int v1 = (t + 256 >= d) ? scn[t + 256 - d] : 0;
        __syncthreads();
        scn[t] += v0;
        scn[t + 256] += v1;
        __syncthreads();
    }
    for (int b = t; b < NB; b += 256) {
        int h  = hist[b];
        int eb = scn[b] - h;
        ebase[b] = eb;
        lcur[b]  = eb;
        gbase[b] = boffs[b] + bpart[b * NCH + blockIdx.x];  // precomputed chunk prefix
    }
    __syncthreads();
#pragma unroll
    for (int i = 0; i < 16; ++i) {
        if (rw[i] >= 0) {
            int b = rw[i] >> RSH;
            int s = atomicAdd(&lcur[b], 1);
            pk[s]  = ((unsigned int)(rw[i] & (RPB - 1)) << 17) | (unsigned int)cl[i];
            gof[s] = gbase[b] + (s - ebase[b]);
        }
    }
    __syncthreads();
    int nval = min(CH, NE - blockIdx.x * CH);
    for (int s = t; s < nval; s += 256) bedge[gof[s]] = pk[s];
}

// ---------------- per-bucket: degree, dinv, offs, per-node CSR ----------------
__global__ __launch_bounds__(256) void k_bucket(const unsigned int* __restrict__ bedge,
                                                const int* __restrict__ boffs,
                                                int* __restrict__ offs,
                                                float* __restrict__ dinv,
                                                int* __restrict__ scol) {
    __shared__ int cnt[RPB];
    __shared__ int loff[RPB];
    __shared__ int wtot[2];
    __shared__ unsigned int ld[CAP];
    __shared__ int buf[CAP];

    int b = blockIdx.x, t = threadIdx.x;
    int beg = boffs[b], end = boffs[b + 1];
    int m = end - beg;
    int nbase = b << RSH;

    if (t < RPB) cnt[t] = 0;
    __syncthreads();

    if (m <= CAP) {
        for (int i = t; i < m; i += 256) {
            unsigned int mm = bedge[beg + i];
            ld[i] = mm;
            atomicAdd(&cnt[mm >> 17], 1);
        }
        __syncthreads();
        if (t < RPB) {
            int v = cnt[t];
            int x = v;
#pragma unroll
            for (int d = 1; d < 64; d <<= 1) {
                int y = __shfl_up(x, d);
                if ((t & 63) >= d) x += y;
            }
            if ((t & 63) == 63) wtot[t >> 6] = x;
            loff[t] = x - v;
        }
        __syncthreads();
        if (t >= 64 && t < RPB) loff[t] += wtot[0];
        __syncthreads();
        if (t < RPB) {
            int n = nbase + t;
            if (n < NN) {
                offs[n] = beg + loff[t];
                dinv[n] = rsqrtf((float)(cnt[t] + 1));
            }
        }
        if (b == NB - 1 && t == 0) offs[NN] = NE;
        if (t < RPB) cnt[t] = loff[t];  // cursors
        __syncthreads();
        for (int i = t; i < m; i += 256) {
            unsigned int mm = ld[i];
            int s = atomicAdd(&cnt[mm >> 17], 1);
            buf[s] = (int)(mm & 0x1FFFFu);
        }
        __syncthreads();
        for (int i = t; i < m; i += 256) scol[beg + i] = buf[i];
    } else {  // fallback (never expected)
        for (int i = t; i < m; i += 256)
            atomicAdd(&cnt[bedge[beg + i] >> 17], 1);
        __syncthreads();
        if (t < RPB) {
            int v = cnt[t];
            int x = v;
#pragma unroll
            for (int d = 1; d < 64; d <<= 1) {
                int y = __shfl_up(x, d);
                if ((t & 63) >= d) x += y;
            }
            if ((t & 63) == 63) wtot[t >> 6] = x;
            loff[t] = x - v;
        }
        __syncthreads();
        if (t >= 64 && t < RPB) loff[t] += wtot[0];
        __syncthreads();
        if (t < RPB) {
            int n = nbase + t;
            if (n < NN) {
                offs[n] = beg + loff[t];
                dinv[n] = rsqrtf((float)(cnt[t] + 1));
            }
        }
        if (b == NB - 1 && t == 0) offs[NN] = NE;
        if (t < RPB) cnt[t] = loff[t];
        __syncthreads();
        for (int i = t; i < m; i += 256) {
            unsigned int mm = bedge[beg + i];
            int s = atomicAdd(&cnt[mm >> 17], 1);
            scol[beg + s] = (int)(mm & 0x1FFFFu);
        }
    }
}

// ---------------- GEMM1: h1s = fp16( dinv[n] * (feat @ W1) ) ----------------
__global__ __launch_bounds__(256) void k_gemm1(const float* __restrict__ feat,
                                               const float* __restrict__ W1,
                                               const float* __restrict__ dinv,
                                               __half* __restrict__ h1s) {
    __shared__ float sW[IN_DIM * HID];
    __shared__ float sF[16][IN_DIM];
    int t = threadIdx.x;

    const float4* W4  = (const float4*)W1;
    float4*       sW4 = (float4*)sW;
#pragma unroll
    for (int i = 0; i < 8; ++i) sW4[t + i * 256] = W4[t + i * 256];

    int n0 = blockIdx.x * 16;
    const float4* F4  = (const float4*)(feat + (size_t)n0 * IN_DIM);
    float4*       sF4 = (float4*)&sF[0][0];
    sF4[t]       = F4[t];
    sF4[t + 256] = F4[t + 256];
    __syncthreads();

    int c = t & 63;
    int g = t >> 6;
    float acc[4] = {0.f, 0.f, 0.f, 0.f};
    for (int k = 0; k < IN_DIM; ++k) {
        float w = sW[k * HID + c];
#pragma unroll
        for (int i = 0; i < 4; ++i) acc[i] += sF[g * 4 + i][k] * w;
    }
#pragma unroll
    for (int i = 0; i < 4; ++i) {
        int n = n0 + g * 4 + i;
        h1s[(size_t)n * HID + c] = __float2half(acc[i] * dinv[n]);
    }
}

// ------- fused agg1: wave/node, lane=(edge-slot, ch-quad), 4 gathers in flight -------
__global__ __launch_bounds__(256) void k_agg1(const int* __restrict__ offs,
                                              const int* __restrict__ scol,
                                              const float* __restrict__ dinv,
                                              const __half* __restrict__ h1s,
                                              const float* __restrict__ b1,
                                              const float* __restrict__ W2,
                                              float* __restrict__ h2s) {
    int n    = blockIdx.x * 4 + (threadIdx.x >> 6);
    int lane = threadIdx.x & 63;
    if (n >= NN) return;
    int g  = lane >> 4;      // edge slot 0..3
    int cq = lane & 15;      // channel quad: channels 4cq..4cq+3
    int beg = offs[n], end = offs[n + 1];

    const uint2* H = (const uint2*)h1s;  // 16 uint2 per 64-ch row
    float a0 = 0.f, a1 = 0.f, a2 = 0.f, a3 = 0.f;
    int k = beg + g;
    for (; k + 12 < end; k += 16) {
        int c0 = scol[k], c1 = scol[k + 4], c2 = scol[k + 8], c3 = scol[k + 12];
        uint2 v0 = H[(size_t)c0 * 16 + cq];
        uint2 v1 = H[(size_t)c1 * 16 + cq];
        uint2 v2 = H[(size_t)c2 * 16 + cq];
        uint2 v3 = H[(size_t)c3 * 16 + cq];
        float2 f0a = __half22float2(*(__half2*)&v0.x), f0b = __half22float2(*(__half2*)&v0.y);
        float2 f1a = __half22float2(*(__half2*)&v1.x), f1b = __half22float2(*(__half2*)&v1.y);
        float2 f2a = __half22float2(*(__half2*)&v2.x), f2b = __half22float2(*(__half2*)&v2.y);
        float2 f3a = __half22float2(*(__half2*)&v3.x), f3b = __half22float2(*(__half2*)&v3.y);
        a0 += (f0a.x + f1a.x) + (f2a.x + f3a.x);
        a1 += (f0a.y + f1a.y) + (f2a.y + f3a.y);
        a2 += (f0b.x + f1b.x) + (f2b.x + f3b.x);
        a3 += (f0b.y + f1b.y) + (f2b.y + f3b.y);
    }
    for (; k < end; k += 4) {
        uint2 v = H[(size_t)scol[k] * 16 + cq];
        float2 fa = __half22float2(*(__half2*)&v.x);
        float2 fb = __half22float2(*(__half2*)&v.y);
        a0 += fa.x; a1 += fa.y; a2 += fb.x; a3 += fb.y;
    }
    // sum over the 4 edge slots
    a0 += __shfl_xor(a0, 16); a0 += __shfl_xor(a0, 32);
    a1 += __shfl_xor(a1, 16); a1 += __shfl_xor(a1, 32);
    a2 += __shfl_xor(a2, 16); a2 += __shfl_xor(a2, 32);
    a3 += __shfl_xor(a3, 16); a3 += __shfl_xor(a3, 32);

    // self loop + dinv[row] scale + bias + relu
    uint2 sv = H[(size_t)n * 16 + cq];
    float2 s0 = __half22float2(*(__half2*)&sv.x);
    float2 s1 = __half22float2(*(__half2*)&sv.y);
    float di = dinv[n];
    float4 b14 = ((const float4*)b1)[cq];
    a0 = fmaxf(di * (a0 + s0.x) + b14.x, 0.f);
    a1 = fmaxf(di * (a1 + s0.y) + b14.y, 0.f);
    a2 = fmaxf(di * (a2 + s1.x) + b14.z, 0.f);
    a3 = fmaxf(di * (a3 + s1.y) + b14.w, 0.f);

    // @W2 (64x2): rows 4cq..4cq+3
    float4 w01 = ((const float4*)W2)[cq * 2];
    float4 w23 = ((const float4*)W2)[cq * 2 + 1];
    float p0 = a0 * w01.x + a1 * w01.z + a2 * w23.x + a3 * w23.z;
    float p1 = a0 * w01.y + a1 * w01.w + a2 * w23.y + a3 * w23.w;
#pragma unroll
    for (int d = 8; d >= 1; d >>= 1) {
        p0 += __shfl_xor(p0, d);
        p1 += __shfl_xor(p1, d);
    }
    if (lane == 0) {
        h2s[(size_t)n * 2 + 0] = di * p0;
        h2s[(size_t)n * 2 + 1] = di * p1;
    }
}

// ---------------- fused agg2: 4 nodes per wave, 16 lanes each ----------------
__global__ __launch_bounds__(256) void k_agg2(const int* __restrict__ offs,
                                              const int* __restrict__ scol,
                                              const float* __restrict__ dinv,
                                              const float* __restrict__ h2s,
                                              const float* __restrict__ b2,
                                              float* __restrict__ emb) {
    int wid  = threadIdx.x >> 6;
    int lane = threadIdx.x & 63;
    int n = blockIdx.x * 16 + wid * 4 + (lane >> 4);
    int e = lane & 15;
    const float2* h22 = (const float2*)h2s;
    float e0 = 0.f, e1 = 0.f;
    int beg = 0, end = 0;
    if (n < NN) { beg = offs[n]; end = offs[n + 1]; }
    for (int k = beg + e; k < end; k += 16) {
        float2 v = h22[scol[k]];
        e0 += v.x;
        e1 += v.y;
    }
#pragma unroll
    for (int d = 8; d >= 1; d >>= 1) {
        e0 += __shfl_xor(e0, d);
        e1 += __shfl_xor(e1, d);
    }
    if (e == 0 && n < NN) {
        float di = dinv[n];
        float2 self = h22[n];
        emb[(size_t)n * 2 + 0] = di * (e0 + self.x) + b2[0];
        emb[(size_t)n * 2 + 1] = di * (e1 + self.y) + b2[1];
    }
}

// ---------------- q = 1/(1 + alpha * d^(2*beta)) ----------------
__global__ void k_q(const int* __restrict__ pr, const int* __restrict__ pc,
                    const int* __restrict__ nr, const int* __restrict__ nc,
                    const float* __restrict__ emb, float* __restrict__ q) {
    int e = blockIdx.x * blockDim.x + threadIdx.x;
    if (e >= 2 * NE) return;
    int a, b;
    if (e < NE) { a = pr[e]; b = pc[e]; }
    else        { a = nr[e - NE]; b = nc[e - NE]; }
    const float2* e2 = (const float2*)emb;
    float2 A = e2[a], B = e2[b];
    float dx = A.x - B.x, dy = A.y - B.y;
    float d = sqrtf(dx * dx + dy * dy + 1e-12f);
    float p = exp2f(2.0f * BETA * log2f(d));
    q[e] = 1.0f / (1.0f + ALPHA * p);
}

extern "C" void kernel_launch(void* const* d_in, const int* in_sizes, int n_in,
                              void* d_out, int out_size, void* d_ws, size_t ws_size,
                              hipStream_t stream) {
    const float* feat = (const float*)d_in[0];
    const float* W1   = (const float*)d_in[1];
    const float* b1   = (const float*)d_in[2];
    const float* W2   = (const float*)d_in[3];
    const float* b2   = (const float*)d_in[4];
    const int*   ei   = (const int*)d_in[5];
    const int*   nrw  = (const int*)d_in[6];
    const int*   ncl  = (const int*)d_in[7];
    const int* row = ei;
    const int* col = ei + NE;

    char* cur = (char*)d_ws;
    auto alloc = [&](size_t bytes) -> char* {
        char* p = cur;
        cur += (bytes + 255) & ~(size_t)255;
        return p;
    };
    int*          bpart = (int*)alloc(sizeof(int) * (size_t)NB * NCH);
    int*          boffs = (int*)alloc(sizeof(int) * (NB + 1));
    int*          offs  = (int*)alloc(sizeof(int) * (NN + 1));
    float*        dinv  = (float*)alloc(sizeof(float) * NN);
    unsigned int* bedge = (unsigned int*)alloc(sizeof(unsigned int) * NE);
    int*          scol  = (int*)alloc(sizeof(int) * NE);
    float*        h2s   = (float*)alloc(sizeof(float) * (size_t)NN * 2);
    __half*       h1s   = (__half*)alloc(sizeof(__half) * (size_t)NN * HID);

    float* emb = (float*)d_out;
    float* q   = (float*)d_out + (size_t)NN * 2;

    k_bhist  <<<NCH, 256, 0, stream>>>(row, bpart);
    k_bscan  <<<1, 256, 0, stream>>>(bpart, boffs);
    k_binfill<<<NCH, 256, 0, stream>>>(row, col, bpart, boffs, bedge);
    k_bucket <<<NB, 256, 0, stream>>>(bedge, boffs, offs, dinv, scol);

    k_gemm1<<<NN / 16, 256, 0, stream>>>(feat, W1, dinv, h1s);

    k_agg1<<<(NN + 3) / 4, 256, 0, stream>>>(offs, scol, dinv, h1s, b1, W2, h2s);
    k_agg2<<<(NN + 15) / 16, 256, 0, stream>>>(offs, scol, dinv, h2s, b2, emb);

    k_q<<<(2 * NE + 255) / 256, 256, 0, stream>>>(row, col, nrw, ncl, emb, q);
}

// Round 10
// 104.889 us; speedup vs baseline: 1.2620x; 1.2620x over previous
//
#include <hip/hip_runtime.h>
#include <hip/hip_fp16.h>
#include <math.h>

constexpr int   NN     = 50000;   // nodes
constexpr int   IN_DIM = 128;
constexpr int   HID    = 64;
constexpr int   NE     = 800000;  // edges
constexpr float ALPHA  = 0.1520f;
constexpr float BETA   = 0.7900f;

constexpr int RSH = 7;                      // rows per bucket = 128
constexpr int RPB = 1 << RSH;
constexpr int NB  = (NN + RPB - 1) / RPB;   // 391 buckets
constexpr int NBP = 512;                    // padded width
constexpr int CH  = 4096;                   // edges per chunk block
constexpr int NCH = (NE + CH - 1) / CH;     // 196
constexpr int CAP = 4096;                   // per-bucket LDS edge capacity

// ---------------- per-chunk bucket histogram -> bpart[b][chunk] ----------------
__global__ __launch_bounds__(256) void k_bhist(const int* __restrict__ row,
                                               int* __restrict__ bpart) {
    __shared__ int h[NBP];
    int t = threadIdx.x;
    for (int i = t; i < NBP; i += 256) h[i] = 0;
    __syncthreads();
    int base = blockIdx.x * CH + t * 16;
    if (base + 15 < NE) {
        const int4* R = (const int4*)(row + base);
#pragma unroll
        for (int i = 0; i < 4; ++i) {
            int4 r = R[i];
            atomicAdd(&h[r.x >> RSH], 1);
            atomicAdd(&h[r.y >> RSH], 1);
            atomicAdd(&h[r.z >> RSH], 1);
            atomicAdd(&h[r.w >> RSH], 1);
        }
    } else {
        for (int i = 0; i < 16; ++i) {
            int e = base + i;
            if (e < NE) atomicAdd(&h[row[e] >> RSH], 1);
        }
    }
    __syncthreads();
    for (int b = t; b < NB; b += 256) bpart[b * NCH + blockIdx.x] = h[b];
}

// ------- parallel per-bucket chunk-prefix: bpart[b][*] -> exclusive, total -> bhist -------
__global__ __launch_bounds__(256) void k_bpre(int* __restrict__ bpart,
                                              int* __restrict__ bhist) {
    __shared__ int s[256];
    int b = blockIdx.x, t = threadIdx.x;
    int v = (t < NCH) ? bpart[b * NCH + t] : 0;
    s[t] = v;
    __syncthreads();
    for (int d = 1; d < 256; d <<= 1) {
        int u = (t >= d) ? s[t - d] : 0;
        __syncthreads();
        s[t] += u;
        __syncthreads();
    }
    if (t < NCH) bpart[b * NCH + t] = s[t] - v;  // exclusive prefix
    if (t == 255) bhist[b] = s[255];             // bucket total
}

// ---------------- exclusive scan of bucket totals -> boffs ----------------
__global__ void k_bscan(const int* __restrict__ bhist, int* __restrict__ boffs) {
    __shared__ int s[NBP];
    int t = threadIdx.x;  // 256
    int v0 = (t < NB) ? bhist[t] : 0;
    int v1 = (t + 256 < NB) ? bhist[t + 256] : 0;
    s[t]       = v0;
    s[t + 256] = v1;
    __syncthreads();
    for (int d = 1; d < NBP; d <<= 1) {
        int u0 = (t >= d) ? s[t - d] : 0;
        int u1 = (t + 256 >= d) ? s[t + 256 - d] : 0;
        __syncthreads();
        s[t] += u0;
        s[t + 256] += u1;
        __syncthreads();
    }
    if (t < NB)       boffs[t]       = s[t] - v0;
    if (t + 256 < NB) boffs[t + 256] = s[t + 256] - v1;
    if (t == 0) boffs[NB] = NE;
}

// ---------------- bucket-sort edges into packed words (no global atomics) ----------------
__global__ __launch_bounds__(256) void k_binfill(const int* __restrict__ row,
                                                 const int* __restrict__ col,
                                                 const int* __restrict__ bpart,
                                                 const int* __restrict__ boffs,
                                                 unsigned int* __restrict__ bedge) {
    __shared__ int hist[NBP];
    __shared__ int scn[NBP];
    __shared__ int ebase[NB];
    __shared__ int gbase[NB];
    __shared__ int lcur[NB];
    __shared__ unsigned int pk[CH];
    __shared__ int gof[CH];

    int t = threadIdx.x;
    int base = blockIdx.x * CH + t * 16;
    int rw[16], cl[16];
    if (base + 15 < NE) {
        const int4* R = (const int4*)(row + base);
        const int4* C = (const int4*)(col + base);
#pragma unroll
        for (int i = 0; i < 4; ++i) {
            int4 r = R[i];
            int4 c = C[i];
            rw[4 * i + 0] = r.x; rw[4 * i + 1] = r.y; rw[4 * i + 2] = r.z; rw[4 * i + 3] = r.w;
            cl[4 * i + 0] = c.x; cl[4 * i + 1] = c.y; cl[4 * i + 2] = c.z; cl[4 * i + 3] = c.w;
        }
    } else {
        for (int i = 0; i < 16; ++i) {
            int e = base + i;
            if (e < NE) { rw[i] = row[e]; cl[i] = col[e]; } else rw[i] = -1;
        }
    }
    for (int i = t; i < NBP; i += 256) hist[i] = 0;
    __syncthreads();
#pragma unroll
    for (int i = 0; i < 16; ++i)
        if (rw[i] >= 0) atomicAdd(&hist[rw[i] >> RSH], 1);
    __syncthreads();
    scn[t] = hist[t];
    scn[t + 256] = hist[t + 256];
    __syncthreads();
    for (int d = 1; d < NBP; d <<= 1) {
        int v0 = (t >= d) ? scn[t - d] : 0;
        int v1 = (t + 256 >= d) ? scn[t + 256 - d] : 0;
        __syncthreads();
        scn[t] += v0;
        scn[t + 256] += v1;
        __syncthreads();
    }
    for (int b = t; b < NB; b += 256) {
        int h  = hist[b];
        int eb = scn[b] - h;
        ebase[b] = eb;
        lcur[b]  = eb;
        gbase[b] = boffs[b] + bpart[b * NCH + blockIdx.x];  // chunk prefix
    }
    __syncthreads();
#pragma unroll
    for (int i = 0; i < 16; ++i) {
        if (rw[i] >= 0) {
            int b = rw[i] >> RSH;
            int s = atomicAdd(&lcur[b], 1);
            pk[s]  = ((unsigned int)(rw[i] & (RPB - 1)) << 17) | (unsigned int)cl[i];
            gof[s] = gbase[b] + (s - ebase[b]);
        }
    }
    __syncthreads();
    int nval = min(CH, NE - blockIdx.x * CH);
    for (int s = t; s < nval; s += 256) bedge[gof[s]] = pk[s];
}

// ---------------- per-bucket: degree, dinv, offs, per-node CSR ----------------
__global__ __launch_bounds__(256) void k_bucket(const unsigned int* __restrict__ bedge,
                                                const int* __restrict__ boffs,
                                                int* __restrict__ offs,
                                                float* __restrict__ dinv,
                                                int* __restrict__ scol) {
    __shared__ int cnt[RPB];
    __shared__ int loff[RPB];
    __shared__ int wtot[2];
    __shared__ unsigned int ld[CAP];
    __shared__ int buf[CAP];

    int b = blockIdx.x, t = threadIdx.x;
    int beg = boffs[b], end = boffs[b + 1];
    int m = end - beg;
    int nbase = b << RSH;

    if (t < RPB) cnt[t] = 0;
    __syncthreads();

    if (m <= CAP) {
        for (int i = t; i < m; i += 256) {
            unsigned int mm = bedge[beg + i];
            ld[i] = mm;
            atomicAdd(&cnt[mm >> 17], 1);
        }
        __syncthreads();
        if (t < RPB) {
            int v = cnt[t];
            int x = v;
#pragma unroll
            for (int d = 1; d < 64; d <<= 1) {
                int y = __shfl_up(x, d);
                if ((t & 63) >= d) x += y;
            }
            if ((t & 63) == 63) wtot[t >> 6] = x;
            loff[t] = x - v;
        }
        __syncthreads();
        if (t >= 64 && t < RPB) loff[t] += wtot[0];
        __syncthreads();
        if (t < RPB) {
            int n = nbase + t;
            if (n < NN) {
                offs[n] = beg + loff[t];
                dinv[n] = rsqrtf((float)(cnt[t] + 1));
            }
        }
        if (b == NB - 1 && t == 0) offs[NN] = NE;
        if (t < RPB) cnt[t] = loff[t];  // cursors
        __syncthreads();
        for (int i = t; i < m; i += 256) {
            unsigned int mm = ld[i];
            int s = atomicAdd(&cnt[mm >> 17], 1);
            buf[s] = (int)(mm & 0x1FFFFu);
        }
        __syncthreads();
        for (int i = t; i < m; i += 256) scol[beg + i] = buf[i];
    } else {  // fallback (never expected)
        for (int i = t; i < m; i += 256)
            atomicAdd(&cnt[bedge[beg + i] >> 17], 1);
        __syncthreads();
        if (t < RPB) {
            int v = cnt[t];
            int x = v;
#pragma unroll
            for (int d = 1; d < 64; d <<= 1) {
                int y = __shfl_up(x, d);
                if ((t & 63) >= d) x += y;
            }
            if ((t & 63) == 63) wtot[t >> 6] = x;
            loff[t] = x - v;
        }
        __syncthreads();
        if (t >= 64 && t < RPB) loff[t] += wtot[0];
        __syncthreads();
        if (t < RPB) {
            int n = nbase + t;
            if (n < NN) {
                offs[n] = beg + loff[t];
                dinv[n] = rsqrtf((float)(cnt[t] + 1));
            }
        }
        if (b == NB - 1 && t == 0) offs[NN] = NE;
        if (t < RPB) cnt[t] = loff[t];
        __syncthreads();
        for (int i = t; i < m; i += 256) {
            unsigned int mm = bedge[beg + i];
            int s = atomicAdd(&cnt[mm >> 17], 1);
            scol[beg + s] = (int)(mm & 0x1FFFFu);
        }
    }
}

// ---------------- GEMM1: h1s = fp16( dinv[n] * (feat @ W1) ) ----------------
__global__ __launch_bounds__(256) void k_gemm1(const float* __restrict__ feat,
                                               const float* __restrict__ W1,
                                               const float* __restrict__ dinv,
                                               __half* __restrict__ h1s) {
    __shared__ float sW[IN_DIM * HID];
    __shared__ float sF[16][IN_DIM];
    int t = threadIdx.x;

    const float4* W4  = (const float4*)W1;
    float4*       sW4 = (float4*)sW;
#pragma unroll
    for (int i = 0; i < 8; ++i) sW4[t + i * 256] = W4[t + i * 256];

    int n0 = blockIdx.x * 16;
    const float4* F4  = (const float4*)(feat + (size_t)n0 * IN_DIM);
    float4*       sF4 = (float4*)&sF[0][0];
    sF4[t]       = F4[t];
    sF4[t + 256] = F4[t + 256];
    __syncthreads();

    int c = t & 63;
    int g = t >> 6;
    float acc[4] = {0.f, 0.f, 0.f, 0.f};
    for (int k = 0; k < IN_DIM; ++k) {
        float w = sW[k * HID + c];
#pragma unroll
        for (int i = 0; i < 4; ++i) acc[i] += sF[g * 4 + i][k] * w;
    }
#pragma unroll
    for (int i = 0; i < 4; ++i) {
        int n = n0 + g * 4 + i;
        h1s[(size_t)n * HID + c] = __float2half(acc[i] * dinv[n]);
    }
}

// ------- fused agg1: wave/node, lane=(edge-slot, ch-quad), 4 gathers in flight -------
__global__ __launch_bounds__(256) void k_agg1(const int* __restrict__ offs,
                                              const int* __restrict__ scol,
                                              const float* __restrict__ dinv,
                                              const __half* __restrict__ h1s,
                                              const float* __restrict__ b1,
                                              const float* __restrict__ W2,
                                              float* __restrict__ h2s) {
    int n    = blockIdx.x * 4 + (threadIdx.x >> 6);
    int lane = threadIdx.x & 63;
    if (n >= NN) return;
    int g  = lane >> 4;      // edge slot 0..3
    int cq = lane & 15;      // channel quad: channels 4cq..4cq+3
    int beg = offs[n], end = offs[n + 1];

    const uint2* H = (const uint2*)h1s;  // 16 uint2 per 64-ch row
    float a0 = 0.f, a1 = 0.f, a2 = 0.f, a3 = 0.f;
    int k = beg + g;
    for (; k + 12 < end; k += 16) {
        int c0 = scol[k], c1 = scol[k + 4], c2 = scol[k + 8], c3 = scol[k + 12];
        uint2 v0 = H[(size_t)c0 * 16 + cq];
        uint2 v1 = H[(size_t)c1 * 16 + cq];
        uint2 v2 = H[(size_t)c2 * 16 + cq];
        uint2 v3 = H[(size_t)c3 * 16 + cq];
        float2 f0a = __half22float2(*(__half2*)&v0.x), f0b = __half22float2(*(__half2*)&v0.y);
        float2 f1a = __half22float2(*(__half2*)&v1.x), f1b = __half22float2(*(__half2*)&v1.y);
        float2 f2a = __half22float2(*(__half2*)&v2.x), f2b = __half22float2(*(__half2*)&v2.y);
        float2 f3a = __half22float2(*(__half2*)&v3.x), f3b = __half22float2(*(__half2*)&v3.y);
        a0 += (f0a.x + f1a.x) + (f2a.x + f3a.x);
        a1 += (f0a.y + f1a.y) + (f2a.y + f3a.y);
        a2 += (f0b.x + f1b.x) + (f2b.x + f3b.x);
        a3 += (f0b.y + f1b.y) + (f2b.y + f3b.y);
    }
    for (; k < end; k += 4) {
        uint2 v = H[(size_t)scol[k] * 16 + cq];
        float2 fa = __half22float2(*(__half2*)&v.x);
        float2 fb = __half22float2(*(__half2*)&v.y);
        a0 += fa.x; a1 += fa.y; a2 += fb.x; a3 += fb.y;
    }
    // sum over the 4 edge slots
    a0 += __shfl_xor(a0, 16); a0 += __shfl_xor(a0, 32);
    a1 += __shfl_xor(a1, 16); a1 += __shfl_xor(a1, 32);
    a2 += __shfl_xor(a2, 16); a2 += __shfl_xor(a2, 32);
    a3 += __shfl_xor(a3, 16); a3 += __shfl_xor(a3, 32);

    // self loop + dinv[row] scale + bias + relu
    uint2 sv = H[(size_t)n * 16 + cq];
    float2 s0 = __half22float2(*(__half2*)&sv.x);
    float2 s1 = __half22float2(*(__half2*)&sv.y);
    float di = dinv[n];
    float4 b14 = ((const float4*)b1)[cq];
    a0 = fmaxf(di * (a0 + s0.x) + b14.x, 0.f);
    a1 = fmaxf(di * (a1 + s0.y) + b14.y, 0.f);
    a2 = fmaxf(di * (a2 + s1.x) + b14.z, 0.f);
    a3 = fmaxf(di * (a3 + s1.y) + b14.w, 0.f);

    // @W2 (64x2): rows 4cq..4cq+3
    float4 w01 = ((const float4*)W2)[cq * 2];
    float4 w23 = ((const float4*)W2)[cq * 2 + 1];
    float p0 = a0 * w01.x + a1 * w01.z + a2 * w23.x + a3 * w23.z;
    float p1 = a0 * w01.y + a1 * w01.w + a2 * w23.y + a3 * w23.w;
#pragma unroll
    for (int d = 8; d >= 1; d >>= 1) {
        p0 += __shfl_xor(p0, d);
        p1 += __shfl_xor(p1, d);
    }
    if (lane == 0) {
        h2s[(size_t)n * 2 + 0] = di * p0;
        h2s[(size_t)n * 2 + 1] = di * p1;
    }
}

// ---------------- fused agg2: 4 nodes per wave, 16 lanes each ----------------
__global__ __launch_bounds__(256) void k_agg2(const int* __restrict__ offs,
                                              const int* __restrict__ scol,
                                              const float* __restrict__ dinv,
                                              const float* __restrict__ h2s,
                                              const float* __restrict__ b2,
                                              float* __restrict__ emb) {
    int wid  = threadIdx.x >> 6;
    int lane = threadIdx.x & 63;
    int n = blockIdx.x * 16 + wid * 4 + (lane >> 4);
    int e = lane & 15;
    const float2* h22 = (const float2*)h2s;
    float e0 = 0.f, e1 = 0.f;
    int beg = 0, end = 0;
    if (n < NN) { beg = offs[n]; end = offs[n + 1]; }
    for (int k = beg + e; k < end; k += 16) {
        float2 v = h22[scol[k]];
        e0 += v.x;
        e1 += v.y;
    }
#pragma unroll
    for (int d = 8; d >= 1; d >>= 1) {
        e0 += __shfl_xor(e0, d);
        e1 += __shfl_xor(e1, d);
    }
    if (e == 0 && n < NN) {
        float di = dinv[n];
        float2 self = h22[n];
        emb[(size_t)n * 2 + 0] = di * (e0 + self.x) + b2[0];
        emb[(size_t)n * 2 + 1] = di * (e1 + self.y) + b2[1];
    }
}

// ---------------- q = 1/(1 + alpha * d^(2*beta)) ----------------
__global__ void k_q(const int* __restrict__ pr, const int* __restrict__ pc,
                    const int* __restrict__ nr, const int* __restrict__ nc,
                    const float* __restrict__ emb, float* __restrict__ q) {
    int e = blockIdx.x * blockDim.x + threadIdx.x;
    if (e >= 2 * NE) return;
    int a, b;
    if (e < NE) { a = pr[e]; b = pc[e]; }
    else        { a = nr[e - NE]; b = nc[e - NE]; }
    const float2* e2 = (const float2*)emb;
    float2 A = e2[a], B = e2[b];
    float dx = A.x - B.x, dy = A.y - B.y;
    float d = sqrtf(dx * dx + dy * dy + 1e-12f);
    float p = exp2f(2.0f * BETA * log2f(d));
    q[e] = 1.0f / (1.0f + ALPHA * p);
}

extern "C" void kernel_launch(void* const* d_in, const int* in_sizes, int n_in,
                              void* d_out, int out_size, void* d_ws, size_t ws_size,
                              hipStream_t stream) {
    const float* feat = (const float*)d_in[0];
    const float* W1   = (const float*)d_in[1];
    const float* b1   = (const float*)d_in[2];
    const float* W2   = (const float*)d_in[3];
    const float* b2   = (const float*)d_in[4];
    const int*   ei   = (const int*)d_in[5];
    const int*   nrw  = (const int*)d_in[6];
    const int*   ncl  = (const int*)d_in[7];
    const int* row = ei;
    const int* col = ei + NE;

    char* cur = (char*)d_ws;
    auto alloc = [&](size_t bytes) -> char* {
        char* p = cur;
        cur += (bytes + 255) & ~(size_t)255;
        return p;
    };
    int*          bpart = (int*)alloc(sizeof(int) * (size_t)NB * NCH);
    int*          bhist = (int*)alloc(sizeof(int) * NB);
    int*          boffs = (int*)alloc(sizeof(int) * (NB + 1));
    int*          offs  = (int*)alloc(sizeof(int) * (NN + 1));
    float*        dinv  = (float*)alloc(sizeof(float) * NN);
    unsigned int* bedge = (unsigned int*)alloc(sizeof(unsigned int) * NE);
    int*          scol  = (int*)alloc(sizeof(int) * NE);
    float*        h2s   = (float*)alloc(sizeof(float) * (size_t)NN * 2);
    __half*       h1s   = (__half*)alloc(sizeof(__half) * (size_t)NN * HID);

    float* emb = (float*)d_out;
    float* q   = (float*)d_out + (size_t)NN * 2;

    k_bhist  <<<NCH, 256, 0, stream>>>(row, bpart);
    k_bpre   <<<NB, 256, 0, stream>>>(bpart, bhist);
    k_bscan  <<<1, 256, 0, stream>>>(bhist, boffs);
    k_binfill<<<NCH, 256, 0, stream>>>(row, col, bpart, boffs, bedge);
    k_bucket <<<NB, 256, 0, stream>>>(bedge, boffs, offs, dinv, scol);

    k_gemm1<<<NN / 16, 256, 0, stream>>>(feat, W1, dinv, h1s);

    k_agg1<<<(NN + 3) / 4, 256, 0, stream>>>(offs, scol, dinv, h1s, b1, W2, h2s);
    k_agg2<<<(NN + 15) / 16, 256, 0, stream>>>(offs, scol, dinv, h2s, b2, emb);

    k_q<<<(2 * NE + 255) / 256, 256, 0, stream>>>(row, col, nrw, ncl, emb, q);
}